// Round 5
// baseline (55.824 us; speedup 1.0000x reference)
//
#include <hip/hip_runtime.h>

#define NN 2048
#define HALF 16777216ull              // B*N*N = 4*2048*2048
#define MLP_BLOCKS 256                // 32 rows each = 8192 rows
#define FILL_BLOCKS 2048              // idx half: 4 rows each
#define ROWS_PER_MLP 32
#define CHUNK 16                      // weight rows staged per chunk (16KB)

typedef float __attribute__((ext_vector_type(4))) f32x4;
typedef float __attribute__((ext_vector_type(2))) f32x2;

// ---------------- Kernel 1: block-specialized MLP + idx-fill ----------------
// blocks [0,256):    shift[row] = 7*(k_net(x_row)+b_kp) for 32 rows (VALU/LDS-bound)
// blocks [256,2304): out[HALF + row*NN + j] = (float)j   (pure HBM writes, overlaps MLP)
__global__ __launch_bounds__(256) void k1_mlp_idx(
    const float* __restrict__ x,
    const float* __restrict__ Wmu1, const float* __restrict__ bmu1,
    const float* __restrict__ Wmu2, const float* __restrict__ bmu2,
    const float* __restrict__ Wkp,  const float* __restrict__ bkp,
    float* __restrict__ out, float* __restrict__ shift)
{
    __shared__ float xs[128][36];      // x tile transposed [d][r], 16B-aligned rows
    __shared__ float h1[256][36];      // h1 transposed [c][r]
    __shared__ float wbuf[CHUNK * 256];

    const int bid  = blockIdx.x;
    const int t    = threadIdx.x;
    const int lane = t & 63;
    const int w    = t >> 6;

    if (bid >= MLP_BLOCKS) {
        // ---- idx-fill path: no barriers, just streams stores ----
        const int row = (bid - MLP_BLOCKS) * 4 + w;
        float* idx = out + HALF + (size_t)row * NN;
        #pragma unroll
        for (int i = 0; i < 8; ++i) {
            const int c = i * 256 + lane * 4;
            f32x4 v = {(float)c, (float)(c + 1), (float)(c + 2), (float)(c + 3)};
            *(f32x4*)(idx + c) = v;
        }
        return;
    }

    // ---- MLP path: wave w owns rows w*8..w*8+7; lane owns cols lane*4..+3 ----
    const int row0 = bid * ROWS_PER_MLP;

    // stage x (32 rows x 128) transposed into xs
    {
        const int r = t >> 3, dq = t & 7;          // 16 floats per thread
        const float* src = x + (size_t)(row0 + r) * 128 + dq * 16;
        #pragma unroll
        for (int q = 0; q < 4; ++q) {
            const f32x4 v = *(const f32x4*)(src + q * 4);
            const int d0 = dq * 16 + q * 4;
            xs[d0 + 0][r] = v[0]; xs[d0 + 1][r] = v[1];
            xs[d0 + 2][r] = v[2]; xs[d0 + 3][r] = v[3];
        }
    }

    f32x4 vb[4];
    auto loadW = [&](const float* gsrc) {          // issue 64B/thread of next chunk
        #pragma unroll
        for (int it = 0; it < 4; ++it)
            vb[it] = *(const f32x4*)(gsrc + it * 1024 + t * 4);
    };
    auto writeW = [&]() {
        #pragma unroll
        for (int it = 0; it < 4; ++it)
            *(f32x4*)(wbuf + it * 1024 + t * 4) = vb[it];
    };

    loadW(Wmu1);                                   // prologue: chunk 0 in regs
    __syncthreads();                               // xs visible

    // ---- layer 1: K=128, 8 chunks of 16 ----
    float acc[8][4] = {};
    for (int c = 0; c < 8; ++c) {
        writeW();
        __syncthreads();                           // wbuf visible
        loadW(c < 7 ? Wmu1 + (c + 1) * CHUNK * 256 : Wmu2);  // hidden under compute
        #pragma unroll
        for (int d = 0; d < CHUNK; ++d) {
            const f32x4 xlo = *(const f32x4*)&xs[c * CHUNK + d][w * 8];      // broadcast
            const f32x4 xhi = *(const f32x4*)&xs[c * CHUNK + d][w * 8 + 4];  // broadcast
            const f32x4 wv  = *(const f32x4*)&wbuf[d * 256 + lane * 4];      // b128
            #pragma unroll
            for (int rr = 0; rr < 4; ++rr)
                #pragma unroll
                for (int j = 0; j < 4; ++j) {
                    acc[rr][j]     = fmaf(xlo[rr], wv[j], acc[rr][j]);
                    acc[rr + 4][j] = fmaf(xhi[rr], wv[j], acc[rr + 4][j]);
                }
        }
        __syncthreads();                           // compute done; wbuf reusable
    }

    // bias + relu -> h1 transposed (f32x2 writes to limit bank conflicts)
    {
        const f32x4 bv = *(const f32x4*)&bmu1[lane * 4];
        #pragma unroll
        for (int j = 0; j < 4; ++j)
            #pragma unroll
            for (int rr = 0; rr < 8; rr += 2) {
                f32x2 v = {fmaxf(acc[rr][j] + bv[j], 0.f),
                           fmaxf(acc[rr + 1][j] + bv[j], 0.f)};
                *(f32x2*)&h1[lane * 4 + j][w * 8 + rr] = v;
            }
    }

    // ---- layer 2: K=256, 16 chunks of 16 ----
    float acc2[8][4] = {};
    for (int c = 0; c < 16; ++c) {
        writeW();
        __syncthreads();                           // wbuf (+h1 when c==0) visible
        if (c < 15) loadW(Wmu2 + (c + 1) * CHUNK * 256);
        #pragma unroll
        for (int d = 0; d < CHUNK; ++d) {
            const f32x4 hlo = *(const f32x4*)&h1[c * CHUNK + d][w * 8];
            const f32x4 hhi = *(const f32x4*)&h1[c * CHUNK + d][w * 8 + 4];
            const f32x4 wv  = *(const f32x4*)&wbuf[d * 256 + lane * 4];
            #pragma unroll
            for (int rr = 0; rr < 4; ++rr)
                #pragma unroll
                for (int j = 0; j < 4; ++j) {
                    acc2[rr][j]     = fmaf(hlo[rr], wv[j], acc2[rr][j]);
                    acc2[rr + 4][j] = fmaf(hhi[rr], wv[j], acc2[rr + 4][j]);
                }
        }
        __syncthreads();
    }

    // ---- bias2 + dot Wkp + wave reduce over cols ----
    {
        const f32x4 b2 = *(const f32x4*)&bmu2[lane * 4];
        const f32x4 wk = *(const f32x4*)&Wkp[lane * 4];
        float p[8];
        #pragma unroll
        for (int rr = 0; rr < 8; ++rr) {
            float s = 0.f;
            #pragma unroll
            for (int j = 0; j < 4; ++j) s = fmaf(acc2[rr][j] + b2[j], wk[j], s);
            p[rr] = s;
        }
        #pragma unroll
        for (int off = 32; off > 0; off >>= 1)
            #pragma unroll
            for (int rr = 0; rr < 8; ++rr) p[rr] += __shfl_xor(p[rr], off, 64);
        if (lane == 0) {
            const float bk = bkp[0];
            #pragma unroll
            for (int rr = 0; rr < 8; ++rr)
                shift[row0 + w * 8 + rr] = 7.0f * (p[rr] + bk);
        }
    }
}

// ---------------- Kernel 2: adj half ----------------
// out[row*NN + j] = sigmoid((2 - 7j) + shift[row])
__global__ __launch_bounds__(256) void k2_adj(
    const float* __restrict__ shift, float* __restrict__ out)
{
    const int t    = threadIdx.x;
    const int lane = t & 63;
    const int w    = t >> 6;
    const int row  = blockIdx.x * 4 + w;
    const float s  = 2.0f + shift[row];

    float* adj = out + (size_t)row * NN;
    #pragma unroll
    for (int i = 0; i < 8; ++i) {
        const int c = i * 256 + lane * 4;
        f32x4 a;
        #pragma unroll
        for (int q = 0; q < 4; ++q) {
            const float z = fmaf(-7.0f, (float)(c + q), s);
            a[q] = 1.0f / (1.0f + __expf(-z));
        }
        *(f32x4*)(adj + c) = a;
    }
}

extern "C" void kernel_launch(void* const* d_in, const int* in_sizes, int n_in,
                              void* d_out, int out_size, void* d_ws, size_t ws_size,
                              hipStream_t stream)
{
    (void)in_sizes; (void)n_in; (void)out_size; (void)ws_size;
    const float* x    = (const float*)d_in[0];
    // d_in[1..5] (temp, W_in, b_in, w_dist, b_dist) are dead code:
    // softmax over a size-1 axis == 1 -> edge_prob == 1/N exactly;
    // stable argsort of all-ties rows == identity permutation.
    const float* Wmu1 = (const float*)d_in[6];
    const float* bmu1 = (const float*)d_in[7];
    const float* Wmu2 = (const float*)d_in[8];
    const float* bmu2 = (const float*)d_in[9];
    const float* Wkp  = (const float*)d_in[10];
    const float* bkp  = (const float*)d_in[11];

    float* shift = (float*)d_ws;      // 8192 floats
    float* out   = (float*)d_out;

    hipLaunchKernelGGL(k1_mlp_idx, dim3(MLP_BLOCKS + FILL_BLOCKS), dim3(256), 0, stream,
                       x, Wmu1, bmu1, Wmu2, bmu2, Wkp, bkp, out, shift);
    hipLaunchKernelGGL(k2_adj, dim3(FILL_BLOCKS), dim3(256), 0, stream,
                       shift, out);
}

// Round 6
// 42.269 us; speedup vs baseline: 1.3207x; 1.3207x over previous
//
#include <hip/hip_runtime.h>

#define NN 2048
#define HALF 16777216ull              // B*N*N = 4*2048*2048

typedef float  __attribute__((ext_vector_type(4))) f32x4;
typedef short  __attribute__((ext_vector_type(8))) s16x8;
typedef ushort __attribute__((ext_vector_type(4))) u16x4;

// fp32 -> bf16 (RTNE) bit trick
__device__ __forceinline__ ushort f2bf(float f) {
    union { float f; uint32_t u; } v; v.f = f;
    const uint32_t r = v.u + 0x7FFFu + ((v.u >> 16) & 1u);
    return (ushort)(r >> 16);
}

// ---------------- k0: weight transpose->bf16 (blocks 0..383) + idx fill ----------------
// w1t[n*128+k] = bf16(Wmu1[k*256+n]);  w2t[n*256+k] = bf16(Wmu2[k*256+n])
// blocks 384..2431: out[HALF + row*NN + j] = (float)j
__global__ __launch_bounds__(256) void k0_prep(
    const float* __restrict__ Wmu1, const float* __restrict__ Wmu2,
    ushort* __restrict__ w1t, ushort* __restrict__ w2t,
    float* __restrict__ out)
{
    const int bid = blockIdx.x, t = threadIdx.x;
    if (bid < 384) {
        const int e = bid * 256 + t;           // 0..98303
        if (e < 32768) {
            const int k = e >> 8, n = e & 255;
            w1t[n * 128 + k] = f2bf(Wmu1[e]);
        } else {
            const int e2 = e - 32768;
            const int k = e2 >> 8, n = e2 & 255;
            w2t[n * 256 + k] = f2bf(Wmu2[e2]);
        }
        return;
    }
    const int lane = t & 63, w = t >> 6;
    const int row = (bid - 384) * 4 + w;
    float* idx = out + HALF + (size_t)row * NN;
    #pragma unroll
    for (int i = 0; i < 8; ++i) {
        const int c = i * 256 + lane * 4;
        f32x4 v = {(float)c, (float)(c + 1), (float)(c + 2), (float)(c + 3)};
        *(f32x4*)(idx + c) = v;
    }
}

// ---------------- k1: MFMA MLP -> shift[8192] ----------------
// Computes h2^T = W2^T·relu(W1^T·x^T + b1) + b2 via mfma_f32_16x16x32_bf16 with
// A = W^T (direct from global, K-contiguous), B = x^T/h1^T (LDS row-major).
// 256 blocks x 256 threads; block owns 32 rows (2 m-tiles); wave owns 4 n-tiles.
__global__ __launch_bounds__(256) void k1_mlp(
    const float* __restrict__ x,
    const ushort* __restrict__ w1t, const float* __restrict__ bmu1,
    const ushort* __restrict__ w2t, const float* __restrict__ bmu2,
    const float* __restrict__ Wkp,  const float* __restrict__ bkp,
    float* __restrict__ shift)
{
    __shared__ ushort xs[32 * 136];   // x rows as bf16, stride 136 (pad 8)
    __shared__ ushort h1[32 * 264];   // h1 rows as bf16, stride 264 (pad 8)
    __shared__ float  red[4][2][16];

    const int t = threadIdx.x, lane = t & 63, w = t >> 6;
    const int l16 = lane & 15, lq = lane >> 4;
    const int row0 = blockIdx.x * 32;

    // stage x (32 rows x 128 fp32) -> bf16 LDS, row-major
    {
        const int r = t >> 3, k0 = (t & 7) * 16;
        const float* src = x + (size_t)(row0 + r) * 128 + k0;
        s16x8 s0, s1;
        #pragma unroll
        for (int q = 0; q < 8; ++q) {
            s0[q] = (short)f2bf(src[q]);
            s1[q] = (short)f2bf(src[8 + q]);
        }
        *(s16x8*)&xs[r * 136 + k0]     = s0;
        *(s16x8*)&xs[r * 136 + k0 + 8] = s1;
    }
    __syncthreads();

    // ---- layer 1: D^T[n][m], K=128 (4 chunks of 32) ----
    f32x4 acc[2][4] = {};             // [mtile][ntile]
    #pragma unroll
    for (int kc = 0; kc < 4; ++kc) {
        const s16x8 b0 = *(const s16x8*)&xs[l16 * 136 + kc * 32 + lq * 8];
        const s16x8 b1 = *(const s16x8*)&xs[(16 + l16) * 136 + kc * 32 + lq * 8];
        #pragma unroll
        for (int nt = 0; nt < 4; ++nt) {
            const int ng = (w * 4 + nt) * 16 + l16;        // W1^T row (= output col)
            const s16x8 a = *(const s16x8*)(w1t + ng * 128 + kc * 32 + lq * 8);
            acc[0][nt] = __builtin_amdgcn_mfma_f32_16x16x32_bf16(a, b0, acc[0][nt], 0, 0, 0);
            acc[1][nt] = __builtin_amdgcn_mfma_f32_16x16x32_bf16(a, b1, acc[1][nt], 0, 0, 0);
        }
    }

    // bias + relu -> h1 (bf16, row-major [m][c]); D: c=(lq*4+reg)+nt*16, m=l16+mt*16
    #pragma unroll
    for (int nt = 0; nt < 4; ++nt) {
        const int c0 = (w * 4 + nt) * 16 + lq * 4;
        const f32x4 bv = *(const f32x4*)&bmu1[c0];
        #pragma unroll
        for (int mt = 0; mt < 2; ++mt) {
            u16x4 hv;
            #pragma unroll
            for (int reg = 0; reg < 4; ++reg)
                hv[reg] = f2bf(fmaxf(acc[mt][nt][reg] + bv[reg], 0.f));
            *(u16x4*)&h1[(mt * 16 + l16) * 264 + c0] = hv;
        }
    }
    __syncthreads();

    // ---- layer 2: K=256 (8 chunks of 32) ----
    f32x4 acc2[2][4] = {};
    #pragma unroll
    for (int kc = 0; kc < 8; ++kc) {
        const s16x8 b0 = *(const s16x8*)&h1[l16 * 264 + kc * 32 + lq * 8];
        const s16x8 b1 = *(const s16x8*)&h1[(16 + l16) * 264 + kc * 32 + lq * 8];
        #pragma unroll
        for (int nt = 0; nt < 4; ++nt) {
            const int ng = (w * 4 + nt) * 16 + l16;        // W2^T row
            const s16x8 a = *(const s16x8*)(w2t + ng * 256 + kc * 32 + lq * 8);
            acc2[0][nt] = __builtin_amdgcn_mfma_f32_16x16x32_bf16(a, b0, acc2[0][nt], 0, 0, 0);
            acc2[1][nt] = __builtin_amdgcn_mfma_f32_16x16x32_bf16(a, b1, acc2[1][nt], 0, 0, 0);
        }
    }

    // ---- (h2 + b2) . wkp, reduce over this wave's 64 cols, then across waves ----
    float p0 = 0.f, p1 = 0.f;
    #pragma unroll
    for (int nt = 0; nt < 4; ++nt) {
        const int c0 = (w * 4 + nt) * 16 + lq * 4;
        const f32x4 b2 = *(const f32x4*)&bmu2[c0];
        const f32x4 wk = *(const f32x4*)&Wkp[c0];
        #pragma unroll
        for (int reg = 0; reg < 4; ++reg) {
            p0 = fmaf(acc2[0][nt][reg] + b2[reg], wk[reg], p0);
            p1 = fmaf(acc2[1][nt][reg] + b2[reg], wk[reg], p1);
        }
    }
    p0 += __shfl_xor(p0, 16, 64);  p0 += __shfl_xor(p0, 32, 64);
    p1 += __shfl_xor(p1, 16, 64);  p1 += __shfl_xor(p1, 32, 64);
    if (lane < 16) { red[w][0][lane] = p0; red[w][1][lane] = p1; }
    __syncthreads();

    if (t < 32) {
        const int mt = t >> 4, m = t & 15;
        const float s = red[0][mt][m] + red[1][mt][m] + red[2][mt][m] + red[3][mt][m];
        shift[row0 + t] = 7.0f * (s + bkp[0]);
    }
}

// ---------------- k2: adj half ----------------
__global__ __launch_bounds__(256) void k2_adj(
    const float* __restrict__ shift, float* __restrict__ out)
{
    const int t = threadIdx.x, lane = t & 63, w = t >> 6;
    const int row = blockIdx.x * 4 + w;
    const float s = 2.0f + shift[row];

    float* adj = out + (size_t)row * NN;
    #pragma unroll
    for (int i = 0; i < 8; ++i) {
        const int c = i * 256 + lane * 4;
        f32x4 a;
        #pragma unroll
        for (int q = 0; q < 4; ++q) {
            const float z = fmaf(-7.0f, (float)(c + q), s);
            a[q] = 1.0f / (1.0f + __expf(-z));
        }
        *(f32x4*)(adj + c) = a;
    }
}

extern "C" void kernel_launch(void* const* d_in, const int* in_sizes, int n_in,
                              void* d_out, int out_size, void* d_ws, size_t ws_size,
                              hipStream_t stream)
{
    (void)in_sizes; (void)n_in; (void)out_size; (void)ws_size;
    const float* x    = (const float*)d_in[0];
    // d_in[1..5] dead: softmax over size-1 axis == 1 -> edge_prob == 1/N exactly;
    // stable argsort of all-ties rows == identity permutation.
    const float* Wmu1 = (const float*)d_in[6];
    const float* bmu1 = (const float*)d_in[7];
    const float* Wmu2 = (const float*)d_in[8];
    const float* bmu2 = (const float*)d_in[9];
    const float* Wkp  = (const float*)d_in[10];
    const float* bkp  = (const float*)d_in[11];

    float*  shift = (float*)d_ws;                             // 32 KB
    ushort* w1t   = (ushort*)((char*)d_ws + 32768);           // 64 KB  (256x128 bf16)
    ushort* w2t   = (ushort*)((char*)d_ws + 32768 + 65536);   // 128 KB (256x256 bf16)
    float*  out   = (float*)d_out;

    hipLaunchKernelGGL(k0_prep, dim3(384 + 2048), dim3(256), 0, stream,
                       Wmu1, Wmu2, w1t, w2t, out);
    hipLaunchKernelGGL(k1_mlp, dim3(256), dim3(256), 0, stream,
                       x, w1t, bmu1, w2t, bmu2, Wkp, bkp, shift);
    hipLaunchKernelGGL(k2_adj, dim3(2048), dim3(256), 0, stream,
                       shift, out);
}

// Round 7
// 37.457 us; speedup vs baseline: 1.4904x; 1.1285x over previous
//
#include <hip/hip_runtime.h>

#define NN 2048
#define HALF 16777216ull              // B*N*N = 4*2048*2048
#define MLP_BLOCKS 256                // 32 rows each

typedef float  __attribute__((ext_vector_type(4))) f32x4;
typedef short  __attribute__((ext_vector_type(8))) s16x8;
typedef ushort __attribute__((ext_vector_type(4))) u16x4;

// fp32 -> bf16 (RTNE)
__device__ __forceinline__ ushort f2bf(float f) {
    union { float f; uint32_t u; } v; v.f = f;
    const uint32_t r = v.u + 0x7FFFu + ((v.u >> 16) & 1u);
    return (ushort)(r >> 16);
}

// ---------------- K1: weight transpose -> bf16 ----------------
// w1t[n*128+k] = bf16(Wmu1[k*256+n]);  w2t[n*256+k] = bf16(Wmu2[k*256+n])
__global__ __launch_bounds__(256) void k1_transpose(
    const float* __restrict__ Wmu1, const float* __restrict__ Wmu2,
    ushort* __restrict__ w1t, ushort* __restrict__ w2t)
{
    const int e = blockIdx.x * 256 + threadIdx.x;   // 0..98303
    if (e < 32768) {
        const int k = e >> 8, n = e & 255;
        w1t[n * 128 + k] = f2bf(Wmu1[e]);
    } else {
        const int e2 = e - 32768;
        const int k = e2 >> 8, n = e2 & 255;
        w2t[n * 256 + k] = f2bf(Wmu2[e2]);
    }
}

// ---------------- K2: block-specialized {MFMA MLP + adj fill} | {idx fill} ----------------
// blocks [0,256):    shift (in LDS) for 32 rows, then adj[row][j] = sigmoid((2-7j)+shift)
// blocks [256,2304): out[HALF + row*NN + j] = (float)j  (4 rows each)
__global__ __launch_bounds__(256) void k2_main(
    const float* __restrict__ x,
    const ushort* __restrict__ w1t, const float* __restrict__ bmu1,
    const ushort* __restrict__ w2t, const float* __restrict__ bmu2,
    const float* __restrict__ Wkp,  const float* __restrict__ bkp,
    float* __restrict__ out)
{
    __shared__ ushort xs[32 * 136];   // x rows bf16, stride 136
    __shared__ ushort h1[32 * 264];   // h1 rows bf16, stride 264
    __shared__ float  red[4][2][16];
    __shared__ float  sh_shift[32];

    const int bid = blockIdx.x, t = threadIdx.x;
    const int lane = t & 63, w = t >> 6;

    if (bid >= MLP_BLOCKS) {
        // ---- idx fill: pure streaming stores ----
        const int row = (bid - MLP_BLOCKS) * 4 + w;
        float* idx = out + HALF + (size_t)row * NN;
        #pragma unroll
        for (int i = 0; i < 8; ++i) {
            const int c = i * 256 + lane * 4;
            f32x4 v = {(float)c, (float)(c + 1), (float)(c + 2), (float)(c + 3)};
            *(f32x4*)(idx + c) = v;
        }
        return;
    }

    // ---- MFMA MLP path (identical math to round 6) ----
    const int l16 = lane & 15, lq = lane >> 4;
    const int row0 = bid * 32;

    // stage x (32 rows x 128 fp32) -> bf16 LDS row-major
    {
        const int r = t >> 3, k0 = (t & 7) * 16;
        const float* src = x + (size_t)(row0 + r) * 128 + k0;
        s16x8 s0, s1;
        #pragma unroll
        for (int q = 0; q < 8; ++q) {
            s0[q] = (short)f2bf(src[q]);
            s1[q] = (short)f2bf(src[8 + q]);
        }
        *(s16x8*)&xs[r * 136 + k0]     = s0;
        *(s16x8*)&xs[r * 136 + k0 + 8] = s1;
    }
    __syncthreads();

    // layer 1: K=128 (4 chunks of 32)
    f32x4 acc[2][4] = {};
    #pragma unroll
    for (int kc = 0; kc < 4; ++kc) {
        const s16x8 b0 = *(const s16x8*)&xs[l16 * 136 + kc * 32 + lq * 8];
        const s16x8 b1 = *(const s16x8*)&xs[(16 + l16) * 136 + kc * 32 + lq * 8];
        #pragma unroll
        for (int nt = 0; nt < 4; ++nt) {
            const int ng = (w * 4 + nt) * 16 + l16;
            const s16x8 a = *(const s16x8*)(w1t + ng * 128 + kc * 32 + lq * 8);
            acc[0][nt] = __builtin_amdgcn_mfma_f32_16x16x32_bf16(a, b0, acc[0][nt], 0, 0, 0);
            acc[1][nt] = __builtin_amdgcn_mfma_f32_16x16x32_bf16(a, b1, acc[1][nt], 0, 0, 0);
        }
    }

    // bias + relu -> h1 bf16 row-major
    #pragma unroll
    for (int nt = 0; nt < 4; ++nt) {
        const int c0 = (w * 4 + nt) * 16 + lq * 4;
        const f32x4 bv = *(const f32x4*)&bmu1[c0];
        #pragma unroll
        for (int mt = 0; mt < 2; ++mt) {
            u16x4 hv;
            #pragma unroll
            for (int reg = 0; reg < 4; ++reg)
                hv[reg] = f2bf(fmaxf(acc[mt][nt][reg] + bv[reg], 0.f));
            *(u16x4*)&h1[(mt * 16 + l16) * 264 + c0] = hv;
        }
    }
    __syncthreads();

    // layer 2: K=256 (8 chunks of 32)
    f32x4 acc2[2][4] = {};
    #pragma unroll
    for (int kc = 0; kc < 8; ++kc) {
        const s16x8 b0 = *(const s16x8*)&h1[l16 * 264 + kc * 32 + lq * 8];
        const s16x8 b1 = *(const s16x8*)&h1[(16 + l16) * 264 + kc * 32 + lq * 8];
        #pragma unroll
        for (int nt = 0; nt < 4; ++nt) {
            const int ng = (w * 4 + nt) * 16 + l16;
            const s16x8 a = *(const s16x8*)(w2t + ng * 256 + kc * 32 + lq * 8);
            acc2[0][nt] = __builtin_amdgcn_mfma_f32_16x16x32_bf16(a, b0, acc2[0][nt], 0, 0, 0);
            acc2[1][nt] = __builtin_amdgcn_mfma_f32_16x16x32_bf16(a, b1, acc2[1][nt], 0, 0, 0);
        }
    }

    // (h2 + b2) . wkp, reduce 64 cols per wave, then across waves
    float p0 = 0.f, p1 = 0.f;
    #pragma unroll
    for (int nt = 0; nt < 4; ++nt) {
        const int c0 = (w * 4 + nt) * 16 + lq * 4;
        const f32x4 b2 = *(const f32x4*)&bmu2[c0];
        const f32x4 wk = *(const f32x4*)&Wkp[c0];
        #pragma unroll
        for (int reg = 0; reg < 4; ++reg) {
            p0 = fmaf(acc2[0][nt][reg] + b2[reg], wk[reg], p0);
            p1 = fmaf(acc2[1][nt][reg] + b2[reg], wk[reg], p1);
        }
    }
    p0 += __shfl_xor(p0, 16, 64);  p0 += __shfl_xor(p0, 32, 64);
    p1 += __shfl_xor(p1, 16, 64);  p1 += __shfl_xor(p1, 32, 64);
    if (lane < 16) { red[w][0][lane] = p0; red[w][1][lane] = p1; }
    __syncthreads();

    if (t < 32) {
        const int mt = t >> 4, m = t & 15;
        const float s = red[0][mt][m] + red[1][mt][m] + red[2][mt][m] + red[3][mt][m];
        sh_shift[t] = 7.0f * (s + bkp[0]) + 2.0f;   // fold the +2 here
    }
    __syncthreads();

    // ---- adj fill for this block's 32 rows: wave w owns rows w*8..w*8+7 ----
    #pragma unroll 2
    for (int rr = 0; rr < 8; ++rr) {
        const int r = w * 8 + rr;
        const float s = sh_shift[r];
        float* adj = out + (size_t)(row0 + r) * NN;
        #pragma unroll
        for (int i = 0; i < 8; ++i) {
            const int c = i * 256 + lane * 4;
            f32x4 a;
            #pragma unroll
            for (int q = 0; q < 4; ++q) {
                const float z = fmaf(-7.0f, (float)(c + q), s);
                a[q] = 1.0f / (1.0f + __expf(-z));
            }
            *(f32x4*)(adj + c) = a;
        }
    }
}

extern "C" void kernel_launch(void* const* d_in, const int* in_sizes, int n_in,
                              void* d_out, int out_size, void* d_ws, size_t ws_size,
                              hipStream_t stream)
{
    (void)in_sizes; (void)n_in; (void)out_size; (void)ws_size;
    const float* x    = (const float*)d_in[0];
    // d_in[1..5] dead: softmax over size-1 axis == 1 -> edge_prob == 1/N exactly;
    // stable argsort of all-ties rows == identity permutation.
    const float* Wmu1 = (const float*)d_in[6];
    const float* bmu1 = (const float*)d_in[7];
    const float* Wmu2 = (const float*)d_in[8];
    const float* bmu2 = (const float*)d_in[9];
    const float* Wkp  = (const float*)d_in[10];
    const float* bkp  = (const float*)d_in[11];

    ushort* w1t = (ushort*)d_ws;                      // 64 KB  (256x128 bf16)
    ushort* w2t = (ushort*)((char*)d_ws + 65536);     // 128 KB (256x256 bf16)
    float*  out = (float*)d_out;

    hipLaunchKernelGGL(k1_transpose, dim3(384), dim3(256), 0, stream,
                       Wmu1, Wmu2, w1t, w2t);
    hipLaunchKernelGGL(k2_main, dim3(MLP_BLOCKS + 2048), dim3(256), 0, stream,
                       x, w1t, bmu1, w2t, bmu2, Wkp, bkp, out);
}